// Round 8
// baseline (485.039 us; speedup 1.0000x reference)
//
#include <hip/hip_runtime.h>

typedef __attribute__((ext_vector_type(8))) short short8;
typedef __attribute__((ext_vector_type(4))) short short4v;
typedef __attribute__((ext_vector_type(4))) float float4v;
typedef __attribute__((ext_vector_type(4))) unsigned uint4v;
typedef __attribute__((ext_vector_type(2))) unsigned uint2v;

constexpr int T  = 2048;
constexpr int DM = 256;
constexpr int DK = 32;

__device__ inline short f2bf(float f) {
  unsigned u = __builtin_bit_cast(unsigned, f);
  u += 0x7fff + ((u >> 16) & 1);            // RNE
  return (short)(u >> 16);
}

__device__ inline unsigned pk2(float a, float b) {
#if __has_builtin(__builtin_amdgcn_cvt_pk_bf16_f32)
  auto r = __builtin_amdgcn_cvt_pk_bf16_f32(a, b);
  return __builtin_bit_cast(unsigned, r);
#else
  unsigned ua = __builtin_bit_cast(unsigned, a);
  ua = (ua + 0x7fff + ((ua >> 16) & 1)) >> 16;
  unsigned ub = __builtin_bit_cast(unsigned, b);
  ub = (ub + 0x7fff + ((ub >> 16) & 1)) >> 16;
  return ua | (ub << 16);
#endif
}

__device__ inline float fexp2(float x) {
#if __has_builtin(__builtin_amdgcn_exp2f)
  return __builtin_amdgcn_exp2f(x);
#else
  return exp2f(x);
#endif
}

__device__ inline short8 load8_bf(const float* __restrict__ p) {
  float4v a = *(const float4v*)p;
  float4v b = *(const float4v*)(p + 4);
  uint4v u;
  u[0] = pk2(a[0], a[1]); u[1] = pk2(a[2], a[3]);
  u[2] = pk2(b[0], b[1]); u[3] = pk2(b[2], b[3]);
  return __builtin_bit_cast(short8, u);
}

// ---------------------------------------------------------------------------
// 128x64-tile NT-GEMM body, fp32 in -> bf16 out, row-major C with bias+scale.
// ---------------------------------------------------------------------------
__device__ inline void gemm_body64(const float* __restrict__ A,
                                   const float* __restrict__ Bw,
                                   const float* __restrict__ bias,
                                   short* __restrict__ C,
                                   float oscale, int bx, int by,
                                   int K, int N,
                                   short (&As)[128][40], short (&Bs)[64][40]) {
  const int tid  = threadIdx.x;
  const int wave = tid >> 6, lane = tid & 63;
  const int l15  = lane & 15, quad = lane >> 4;
  const int wm   = (wave & 1) * 64, wn = (wave >> 1) * 32;
  const long Abase = (long)bx * 128;
  const long Bbase = (long)by * 64;

  float4v acc[4][2];
  for (int i = 0; i < 4; i++)
    for (int j = 0; j < 2; j++)
      for (int r = 0; r < 4; r++) acc[i][j][r] = 0.f;

  const int srow = tid >> 2;
  const int sc8  = (tid & 3) * 8;

  for (int k0 = 0; k0 < K; k0 += 32) {
    __syncthreads();
    for (int i = 0; i < 2; i++) {
      int row = srow + i * 64;
      *(short8*)&As[row][sc8] = load8_bf(A + (Abase + row) * K + k0 + sc8);
    }
    *(short8*)&Bs[srow][sc8] = load8_bf(Bw + (Bbase + srow) * K + k0 + sc8);
    __syncthreads();
    short8 af[4], bfr[2];
    for (int ms = 0; ms < 4; ms++) af[ms]  = *(const short8*)&As[wm + ms*16 + l15][quad*8];
    for (int ns = 0; ns < 2; ns++) bfr[ns] = *(const short8*)&Bs[wn + ns*16 + l15][quad*8];
    for (int ms = 0; ms < 4; ms++)
      for (int ns = 0; ns < 2; ns++)
        acc[ms][ns] = __builtin_amdgcn_mfma_f32_16x16x32_bf16(af[ms], bfr[ns], acc[ms][ns], 0, 0, 0);
  }

  for (int ms = 0; ms < 4; ms++) {
    int rowl = wm + ms*16 + quad*4;
    for (int ns = 0; ns < 2; ns++) {
      int col = (int)Bbase + wn + ns*16 + l15;
      float bv = bias[col];
      for (int r = 0; r < 4; r++) {
        long row = Abase + rowl + r;
        C[row * (long)N + col] = f2bf((acc[ms][ns][r] + bv) * oscale);
      }
    }
  }
}

// ---------------------------------------------------------------------------
// prep kernel (616 blocks):
//  [0,256)   : K projection  -> Kp  [8192][256] bf16
//  [256,512) : Q projection  -> Qp  (x log2e)
//  [512,576) : Wfused[h][n][k] = sum_d WO_w[n,d*8+h] * WV_w[h*256+d,k]  (bf16)
//  [576,584) : cbias[h][n]   = sum_d WV_b[h*256+d] * WO_w[n,d*8+h]      (fp32)
//  [584,616) : out prefill with WO_b
// ---------------------------------------------------------------------------
__global__ __launch_bounds__(256)
void prep(const float* __restrict__ key_x, const float* __restrict__ query_x,
          const float* __restrict__ WK_w, const float* __restrict__ WK_b,
          const float* __restrict__ WQ_w, const float* __restrict__ WQ_b,
          const float* __restrict__ WV_w, const float* __restrict__ WV_b,
          const float* __restrict__ WO_w, const float* __restrict__ WO_b,
          short* __restrict__ Kp, short* __restrict__ Qp,
          short* __restrict__ Wf, float* __restrict__ cbias,
          float* __restrict__ outp) {
  __shared__ __align__(16) short As[128][40];
  __shared__ __align__(16) short Bs[64][40];

  const int gb  = blockIdx.x;
  const int tid = threadIdx.x;

  if (gb < 512) {
    const int g = gb & 255;
    const int bx = g & 63, by = g >> 6;
    if (gb < 256)
      gemm_body64(key_x,   WK_w, WK_b, Kp, 1.0f,        bx, by, 256, 256, As, Bs);
    else
      gemm_body64(query_x, WQ_w, WQ_b, Qp, 1.44269504f, bx, by, 256, 256, As, Bs);
  } else if (gb < 576) {
    // Wfused: per-head NN-GEMM [256n x 256d] x [256d x 256k]
    const int w  = gb - 512;
    const int h  = w >> 3;
    const int bx = (w >> 2) & 1;        // 2 m-tiles (n)
    const int by = w & 3;               // 4 n'-tiles (k)
    const int wave = tid >> 6, lane = tid & 63;
    const int l15  = lane & 15, quad = lane >> 4;
    const int wm   = (wave & 1) * 64, wn = (wave >> 1) * 32;
    const int srow = tid >> 2, sc8 = (tid & 3) * 8;

    float4v acc[4][2];
    for (int i = 0; i < 4; i++)
      for (int j = 0; j < 2; j++)
        for (int r = 0; r < 4; r++) acc[i][j][r] = 0.f;

    for (int d0 = 0; d0 < 256; d0 += 32) {
      __syncthreads();
      for (int i = 0; i < 2; i++) {
        int row = srow + i * 64;        // n within tile
        for (int j = 0; j < 8; j++)
          As[row][sc8 + j] = f2bf(WO_w[(bx*128 + row) * 2048 + (d0 + sc8 + j) * 8 + h]);
      }
      for (int j = 0; j < 8; j++)       // Bs[k][d] = WV_w[h*256+d][k] transposed
        Bs[srow][sc8 + j] = f2bf(WV_w[((h*256) + d0 + sc8 + j) * 256 + by*64 + srow]);
      __syncthreads();
      short8 af[4], bfr[2];
      for (int ms = 0; ms < 4; ms++) af[ms]  = *(const short8*)&As[wm + ms*16 + l15][quad*8];
      for (int ns = 0; ns < 2; ns++) bfr[ns] = *(const short8*)&Bs[wn + ns*16 + l15][quad*8];
      for (int ms = 0; ms < 4; ms++)
        for (int ns = 0; ns < 2; ns++)
          acc[ms][ns] = __builtin_amdgcn_mfma_f32_16x16x32_bf16(af[ms], bfr[ns], acc[ms][ns], 0, 0, 0);
    }
    for (int ms = 0; ms < 4; ms++) {
      int m = bx*128 + wm + ms*16 + quad*4;
      for (int ns = 0; ns < 2; ns++) {
        int col = by*64 + wn + ns*16 + l15;
        for (int r = 0; r < 4; r++)
          Wf[((long)h*256 + m + r) * 256 + col] = f2bf(acc[ms][ns][r]);
      }
    }
  } else if (gb < 584) {
    // cbias[h][n]
    const int h = gb - 576;
    const int n = tid;
    float acc = 0.f;
    for (int d = 0; d < 256; d++)
      acc += WV_b[h*256 + d] * WO_w[n * 2048 + d*8 + h];
    cbias[h*256 + n] = acc;
  } else {
    // out prefill with WO_b: rows [p*256, p*256+256)
    const int p  = gb - 584;
    const int c4 = (tid & 63) * 4;
    const int r0 = tid >> 6;
    float4v bv = *(const float4v*)(WO_b + c4);
    for (int i = 0; i < 64; i++) {
      long row = (long)p*256 + r0*64 + i;
      *(float4v*)(outp + row*256 + c4) = bv;
    }
  }
}

// ---------------------------------------------------------------------------
// Ut GEMM: Ut[b][h*256+n][s] = sum_k Wf[h*256+n][k] * value_x[b*2048+s][k]
// A bf16 [2048][256] (direct loads), B fp32 (convert at staging). No bias.
// Grid (16, 128): 128-row x 64-col tiles; mode-1 style scattered store.
// ---------------------------------------------------------------------------
__global__ __launch_bounds__(256)
void gemm_ut(const short* __restrict__ Wf, const float* __restrict__ Bw,
             short* __restrict__ Ut) {
  __shared__ __align__(16) short As[128][40];
  __shared__ __align__(16) short Bs[64][40];

  const int tid  = threadIdx.x;
  const int wave = tid >> 6, lane = tid & 63;
  const int l15  = lane & 15, quad = lane >> 4;
  const int wm   = (wave & 1) * 64, wn = (wave >> 1) * 32;
  const long Abase = (long)blockIdx.x * 128;
  const long Bbase = (long)blockIdx.y * 64;

  float4v acc[4][2];
  for (int i = 0; i < 4; i++)
    for (int j = 0; j < 2; j++)
      for (int r = 0; r < 4; r++) acc[i][j][r] = 0.f;

  const int srow = tid >> 2;
  const int sc8  = (tid & 3) * 8;

  for (int k0 = 0; k0 < 256; k0 += 32) {
    __syncthreads();
    for (int i = 0; i < 2; i++) {
      int row = srow + i * 64;
      *(short8*)&As[row][sc8] = *(const short8*)(Wf + (Abase + row) * 256 + k0 + sc8);
    }
    *(short8*)&Bs[srow][sc8] = load8_bf(Bw + (Bbase + srow) * 256 + k0 + sc8);
    __syncthreads();
    short8 af[4], bfr[2];
    for (int ms = 0; ms < 4; ms++) af[ms]  = *(const short8*)&As[wm + ms*16 + l15][quad*8];
    for (int ns = 0; ns < 2; ns++) bfr[ns] = *(const short8*)&Bs[wn + ns*16 + l15][quad*8];
    for (int ms = 0; ms < 4; ms++)
      for (int ns = 0; ns < 2; ns++)
        acc[ms][ns] = __builtin_amdgcn_mfma_f32_16x16x32_bf16(af[ms], bfr[ns], acc[ms][ns], 0, 0, 0);
  }

  for (int ms = 0; ms < 4; ms++) {
    int rowl = wm + ms*16 + quad*4;
    for (int ns = 0; ns < 2; ns++) {
      int col = (int)Bbase + wn + ns*16 + l15;
      int bidx = col >> 11, scol = col & 2047;
      for (int r = 0; r < 4; r++) {
        long m = Abase + rowl + r;
        Ut[((long)bidx * 2048 + m) * 2048 + scol] = f2bf(acc[ms][ns][r]);
      }
    }
  }
}

// ---------------------------------------------------------------------------
// Fused attention + output projection. r3/r7 structure; PV now contracts
// with Ut = V·WO^T per head, so acc IS the output-feature tile. Epilogue:
// normalize by l, add per-head cbias, atomicAdd into out (prefilled w/ WO_b).
// Grid 512 linear; h = id%8 (XCD head locality for Ut).
// ---------------------------------------------------------------------------
__global__ __launch_bounds__(256, 2)
void attn_kernel(const short* __restrict__ Kp, const short* __restrict__ Qp,
                 const short* __restrict__ Ut, const float* __restrict__ cbias,
                 float* __restrict__ outp) {
  __shared__ __align__(16) short Pt[2][128][136];
  __shared__ __align__(16) float psum[128][4];

  const int tid  = threadIdx.x;
  const int wave = tid >> 6, lane = tid & 63;
  const int l15  = lane & 15, quad = lane >> 4;

  const int L  = blockIdx.x;
  const int h  = L & 7;
  const int b  = (L >> 3) & 3;
  const int q0 = (L >> 5) * 128;

  const short* Kbh = Kp + (long)b * T * DM + h * DK;
  const short* Qbh = Qp + (long)b * T * DM + h * DK;
  const short* Ubh = Ut + ((long)b * 2048 + h * 256) * 2048;
  const float* cb  = cbias + h * 256;

  float4v acc[4][8];
  for (int i = 0; i < 4; i++)
    for (int j = 0; j < 8; j++)
      for (int r = 0; r < 4; r++) acc[i][j][r] = 0.f;

  float ps[8];
  for (int i = 0; i < 8; i++) ps[i] = 0.f;

  short8 qf[8];                       // Q fragments: loaded once, persistent
  for (int qs = 0; qs < 8; qs++)
    qf[qs] = *(const short8*)(Qbh + (long)(q0 + qs*16 + l15) * DM + quad*8);

  auto computeSt = [&](int s0, int buf) {
    for (int ss = 0; ss < 2; ss++) {
      short8 kf = *(const short8*)(Kbh + (long)(s0 + wave*32 + ss*16 + l15) * DM + quad*8);
      for (int qs = 0; qs < 8; qs++) {
        float4v z = {0.f, 0.f, 0.f, 0.f};
        float4v st = __builtin_amdgcn_mfma_f32_16x16x32_bf16(kf, qf[qs], z, 0, 0, 0);
        float p0 = fexp2(st[0]), p1 = fexp2(st[1]);
        float p2 = fexp2(st[2]), p3 = fexp2(st[3]);
        ps[qs] += (p0 + p1) + (p2 + p3);
        uint2v pb; pb[0] = pk2(p0, p1); pb[1] = pk2(p2, p3);
        *(uint2v*)&Pt[buf][qs*16 + l15][wave*32 + ss*16 + quad*4] = pb;
      }
    }
  };

  computeSt(0, 0);

  for (int it = 0; it < T / 128; it++) {
    const int buf = it & 1;
    const int s0  = it * 128;
    __syncthreads();
    if (it < T / 128 - 1) computeSt(s0 + 128, buf ^ 1);
    for (int ks = 0; ks < 4; ks++) {
      short8 pf[8];
      for (int ns = 0; ns < 8; ns++)
        pf[ns] = *(const short8*)&Pt[buf][ns*16 + l15][ks*32 + quad*8];
      for (int ms = 0; ms < 4; ms++) {
        short8 vf = *(const short8*)(Ubh + (long)(wave*64 + ms*16 + l15) * 2048
                                     + s0 + ks*32 + quad*8);
        for (int ns = 0; ns < 8; ns++)
          acc[ms][ns] = __builtin_amdgcn_mfma_f32_16x16x32_bf16(vf, pf[ns], acc[ms][ns], 0, 0, 0);
      }
    }
  }

  for (int qs = 0; qs < 8; qs++) {
    ps[qs] += __shfl_xor(ps[qs], 16, 64);
    ps[qs] += __shfl_xor(ps[qs], 32, 64);
  }
  if (lane < 16)
    for (int qs = 0; qs < 8; qs++) psum[qs*16 + lane][wave] = ps[qs];
  __syncthreads();

  for (int ns = 0; ns < 8; ns++) {
    float4v sv = *(const float4v*)&psum[ns*16 + l15][0];
    float rl = 1.0f / (sv[0] + sv[1] + sv[2] + sv[3]);
    long rowbase = ((long)(b * T + q0 + ns*16 + l15)) * 256;
    for (int ms = 0; ms < 4; ms++) {
      int ncol = wave*64 + ms*16 + quad*4;
      for (int r = 0; r < 4; r++)
        atomicAdd(outp + rowbase + ncol + r, acc[ms][ns][r] * rl + cb[ncol + r]);
    }
  }
}

// ---------------------------------------------------------------------------
extern "C" void kernel_launch(void* const* d_in, const int* in_sizes, int n_in,
                              void* d_out, int out_size, void* d_ws, size_t ws_size,
                              hipStream_t stream) {
  const float* key_x   = (const float*)d_in[0];
  const float* query_x = (const float*)d_in[1];
  const float* value_x = (const float*)d_in[2];
  const float* WK_w = (const float*)d_in[4];
  const float* WK_b = (const float*)d_in[5];
  const float* WQ_w = (const float*)d_in[6];
  const float* WQ_b = (const float*)d_in[7];
  const float* WV_w = (const float*)d_in[8];
  const float* WV_b = (const float*)d_in[9];
  const float* WO_w = (const float*)d_in[10];
  const float* WO_b = (const float*)d_in[11];

  char* ws = (char*)d_ws;
  short* Kp    = (short*)(ws);                  //  4 MB  [8192][256] bf16
  short* Qp    = (short*)(ws + (4u  << 20));    //  4 MB  [8192][256] bf16 (x log2e)
  short* Ut    = (short*)(ws + (8u  << 20));    // 32 MB  [4][2048][2048] bf16
  short* Wf    = (short*)(ws + (40u << 20));    //  1 MB  [8*256][256] bf16
  float* cbias = (float*)(ws + (41u << 20));    //  8 KB  [8][256] fp32
  float* outp  = (float*)d_out;

  prep<<<616, 256, 0, stream>>>(key_x, query_x, WK_w, WK_b, WQ_w, WQ_b,
                                WV_w, WV_b, WO_w, WO_b,
                                Kp, Qp, Wf, cbias, outp);
  gemm_ut<<<dim3(16, 128), 256, 0, stream>>>(Wf, value_x, Ut);
  attn_kernel<<<dim3(512), 256, 0, stream>>>(Kp, Qp, Ut, cbias, outp);
}

// Round 9
// 295.688 us; speedup vs baseline: 1.6404x; 1.6404x over previous
//
#include <hip/hip_runtime.h>

typedef __attribute__((ext_vector_type(8))) short short8;
typedef __attribute__((ext_vector_type(4))) short short4v;
typedef __attribute__((ext_vector_type(4))) float float4v;
typedef __attribute__((ext_vector_type(4))) unsigned uint4v;
typedef __attribute__((ext_vector_type(2))) unsigned uint2v;
typedef __attribute__((ext_vector_type(4))) _Float16 half4;

constexpr int T  = 2048;
constexpr int DM = 256;
constexpr int DK = 32;

__device__ inline short f2bf(float f) {
  unsigned u = __builtin_bit_cast(unsigned, f);
  u += 0x7fff + ((u >> 16) & 1);            // RNE
  return (short)(u >> 16);
}

__device__ inline unsigned pk2(float a, float b) {
#if __has_builtin(__builtin_amdgcn_cvt_pk_bf16_f32)
  auto r = __builtin_amdgcn_cvt_pk_bf16_f32(a, b);
  return __builtin_bit_cast(unsigned, r);
#else
  unsigned ua = __builtin_bit_cast(unsigned, a);
  ua = (ua + 0x7fff + ((ua >> 16) & 1)) >> 16;
  unsigned ub = __builtin_bit_cast(unsigned, b);
  ub = (ub + 0x7fff + ((ub >> 16) & 1)) >> 16;
  return ua | (ub << 16);
#endif
}

__device__ inline float fexp2(float x) {
#if __has_builtin(__builtin_amdgcn_exp2f)
  return __builtin_amdgcn_exp2f(x);
#else
  return exp2f(x);
#endif
}

__device__ inline short8 load8_bf(const float* __restrict__ p) {
  float4v a = *(const float4v*)p;
  float4v b = *(const float4v*)(p + 4);
  uint4v u;
  u[0] = pk2(a[0], a[1]); u[1] = pk2(a[2], a[3]);
  u[2] = pk2(b[0], b[1]); u[3] = pk2(b[2], b[3]);
  return __builtin_bit_cast(short8, u);
}

// ---------------------------------------------------------------------------
// 128x64-tile NT-GEMM body, fp32 in -> bf16 out, row-major C with bias+scale.
// ---------------------------------------------------------------------------
__device__ inline void gemm_body64(const float* __restrict__ A,
                                   const float* __restrict__ Bw,
                                   const float* __restrict__ bias,
                                   short* __restrict__ C,
                                   float oscale, int bx, int by,
                                   int K, int N,
                                   short (&As)[128][40], short (&Bs)[64][40]) {
  const int tid  = threadIdx.x;
  const int wave = tid >> 6, lane = tid & 63;
  const int l15  = lane & 15, quad = lane >> 4;
  const int wm   = (wave & 1) * 64, wn = (wave >> 1) * 32;
  const long Abase = (long)bx * 128;
  const long Bbase = (long)by * 64;

  float4v acc[4][2];
  for (int i = 0; i < 4; i++)
    for (int j = 0; j < 2; j++)
      for (int r = 0; r < 4; r++) acc[i][j][r] = 0.f;

  const int srow = tid >> 2;
  const int sc8  = (tid & 3) * 8;

  for (int k0 = 0; k0 < K; k0 += 32) {
    __syncthreads();
    for (int i = 0; i < 2; i++) {
      int row = srow + i * 64;
      *(short8*)&As[row][sc8] = load8_bf(A + (Abase + row) * K + k0 + sc8);
    }
    *(short8*)&Bs[srow][sc8] = load8_bf(Bw + (Bbase + srow) * K + k0 + sc8);
    __syncthreads();
    short8 af[4], bfr[2];
    for (int ms = 0; ms < 4; ms++) af[ms]  = *(const short8*)&As[wm + ms*16 + l15][quad*8];
    for (int ns = 0; ns < 2; ns++) bfr[ns] = *(const short8*)&Bs[wn + ns*16 + l15][quad*8];
    for (int ms = 0; ms < 4; ms++)
      for (int ns = 0; ns < 2; ns++)
        acc[ms][ns] = __builtin_amdgcn_mfma_f32_16x16x32_bf16(af[ms], bfr[ns], acc[ms][ns], 0, 0, 0);
  }

  for (int ms = 0; ms < 4; ms++) {
    int rowl = wm + ms*16 + quad*4;
    for (int ns = 0; ns < 2; ns++) {
      int col = (int)Bbase + wn + ns*16 + l15;
      float bv = bias[col];
      for (int r = 0; r < 4; r++) {
        long row = Abase + rowl + r;
        C[row * (long)N + col] = f2bf((acc[ms][ns][r] + bv) * oscale);
      }
    }
  }
}

// ---------------------------------------------------------------------------
// prep kernel (704 blocks):
//  [0,256)   : K projection  -> Kp  [8192][256] bf16
//  [256,512) : Q projection  -> Qp  (x log2e)
//  [512,576) : Wfused[h][n][k] = sum_d WO_w[n,d*8+h] * WV_w[h*256+d,k]  (bf16)
//  [576,704) : cbias[h][n]   = sum_d WV_b[h*256+d] * WO_w[n,d*8+h]      (fp32)
// ---------------------------------------------------------------------------
__global__ __launch_bounds__(256)
void prep(const float* __restrict__ key_x, const float* __restrict__ query_x,
          const float* __restrict__ WK_w, const float* __restrict__ WK_b,
          const float* __restrict__ WQ_w, const float* __restrict__ WQ_b,
          const float* __restrict__ WV_w, const float* __restrict__ WV_b,
          const float* __restrict__ WO_w,
          short* __restrict__ Kp, short* __restrict__ Qp,
          short* __restrict__ Wf, float* __restrict__ cbias) {
  __shared__ __align__(16) short As[128][40];
  __shared__ __align__(16) short Bs[64][40];
  __shared__ float cb_s[16][17];

  const int gb  = blockIdx.x;
  const int tid = threadIdx.x;

  if (gb < 512) {
    const int g = gb & 255;
    const int bx = g & 63, by = g >> 6;
    if (gb < 256)
      gemm_body64(key_x,   WK_w, WK_b, Kp, 1.0f,        bx, by, 256, 256, As, Bs);
    else
      gemm_body64(query_x, WQ_w, WQ_b, Qp, 1.44269504f, bx, by, 256, 256, As, Bs);
  } else if (gb < 576) {
    // Wfused: per-head NN-GEMM [256n x 256d] x [256d x 256k]
    const int w  = gb - 512;
    const int h  = w >> 3;
    const int bx = (w >> 2) & 1;        // 2 m-tiles (n)
    const int by = w & 3;               // 4 k-tiles
    const int wave = tid >> 6, lane = tid & 63;
    const int l15  = lane & 15, quad = lane >> 4;
    const int wm   = (wave & 1) * 64, wn = (wave >> 1) * 32;
    const int srow = tid >> 2, sc8 = (tid & 3) * 8;

    float4v acc[4][2];
    for (int i = 0; i < 4; i++)
      for (int j = 0; j < 2; j++)
        for (int r = 0; r < 4; r++) acc[i][j][r] = 0.f;

    for (int d0 = 0; d0 < 256; d0 += 32) {
      __syncthreads();
      for (int i = 0; i < 2; i++) {
        int row = srow + i * 64;        // n within tile
        for (int j = 0; j < 8; j++)
          As[row][sc8 + j] = f2bf(WO_w[(bx*128 + row) * 2048 + (d0 + sc8 + j) * 8 + h]);
      }
      for (int j = 0; j < 8; j++)       // Bs[k][d] = WV_w[h*256+d][k] transposed
        Bs[srow][sc8 + j] = f2bf(WV_w[((h*256) + d0 + sc8 + j) * 256 + by*64 + srow]);
      __syncthreads();
      short8 af[4], bfr[2];
      for (int ms = 0; ms < 4; ms++) af[ms]  = *(const short8*)&As[wm + ms*16 + l15][quad*8];
      for (int ns = 0; ns < 2; ns++) bfr[ns] = *(const short8*)&Bs[wn + ns*16 + l15][quad*8];
      for (int ms = 0; ms < 4; ms++)
        for (int ns = 0; ns < 2; ns++)
          acc[ms][ns] = __builtin_amdgcn_mfma_f32_16x16x32_bf16(af[ms], bfr[ns], acc[ms][ns], 0, 0, 0);
    }
    for (int ms = 0; ms < 4; ms++) {
      int m = bx*128 + wm + ms*16 + quad*4;
      for (int ns = 0; ns < 2; ns++) {
        int col = by*64 + wn + ns*16 + l15;
        for (int r = 0; r < 4; r++)
          Wf[((long)h*256 + m + r) * 256 + col] = f2bf(acc[ms][ns][r]);
      }
    }
  } else {
    // cbias[h][n]: 128 blocks, 16n x 16d threads, LDS reduce over d-lanes
    const int idx = gb - 576;
    const int h = idx >> 4, ng = idx & 15;
    const int ni = tid & 15, di = tid >> 4;
    const int n = ng * 16 + ni;
    float acc = 0.f;
    for (int j = 0; j < 16; j++) {
      int d = di * 16 + j;
      acc += WV_b[h*256 + d] * WO_w[n * 2048 + d*8 + h];
    }
    cb_s[ni][di] = acc;
    __syncthreads();
    if (tid < 16) {
      float s = 0.f;
      for (int d2 = 0; d2 < 16; d2++) s += cb_s[tid][d2];
      cbias[h*256 + ng*16 + tid] = s;
    }
  }
}

// ---------------------------------------------------------------------------
// Ut GEMM: Ut[b][h*256+n][s] = sum_k Wf[h*256+n][k]*value_x[b*2048+s][k]
//                              + cbias[h*256+n]
// A bf16 [2048][256] direct; B fp32 (convert at staging). 128x128 tiles,
// grid (16, 64) = 1024 blocks. Mode-1 scattered store into [4][2048][2048].
// ---------------------------------------------------------------------------
__global__ __launch_bounds__(256)
void gemm_ut(const short* __restrict__ Wf, const float* __restrict__ Bw,
             const float* __restrict__ cbias, short* __restrict__ Ut) {
  __shared__ __align__(16) short As[128][40];
  __shared__ __align__(16) short Bs[128][40];

  const int tid  = threadIdx.x;
  const int wave = tid >> 6, lane = tid & 63;
  const int l15  = lane & 15, quad = lane >> 4;
  const int wm   = (wave & 1) * 64, wn = (wave >> 1) * 64;
  const long Abase = (long)blockIdx.x * 128;
  const long Bbase = (long)blockIdx.y * 128;

  float4v acc[4][4];
  for (int i = 0; i < 4; i++)
    for (int j = 0; j < 4; j++)
      for (int r = 0; r < 4; r++) acc[i][j][r] = 0.f;

  const int srow = tid >> 2;
  const int sc8  = (tid & 3) * 8;

  for (int k0 = 0; k0 < 256; k0 += 32) {
    __syncthreads();
    for (int i = 0; i < 2; i++) {
      int row = srow + i * 64;
      *(short8*)&As[row][sc8] = *(const short8*)(Wf + (Abase + row) * 256 + k0 + sc8);
      *(short8*)&Bs[row][sc8] = load8_bf(Bw + (Bbase + row) * 256 + k0 + sc8);
    }
    __syncthreads();
    short8 af[4], bfr[4];
    for (int ms = 0; ms < 4; ms++) af[ms]  = *(const short8*)&As[wm + ms*16 + l15][quad*8];
    for (int ns = 0; ns < 4; ns++) bfr[ns] = *(const short8*)&Bs[wn + ns*16 + l15][quad*8];
    for (int ms = 0; ms < 4; ms++)
      for (int ns = 0; ns < 4; ns++)
        acc[ms][ns] = __builtin_amdgcn_mfma_f32_16x16x32_bf16(af[ms], bfr[ns], acc[ms][ns], 0, 0, 0);
  }

  for (int ms = 0; ms < 4; ms++) {
    int rowl = wm + ms*16 + quad*4;
    for (int ns = 0; ns < 4; ns++) {
      int col = (int)Bbase + wn + ns*16 + l15;
      int bidx = col >> 11, scol = col & 2047;
      for (int r = 0; r < 4; r++) {
        long m = Abase + rowl + r;
        Ut[((long)bidx * 2048 + m) * 2048 + scol] = f2bf(acc[ms][ns][r] + cbias[m]);
      }
    }
  }
}

// ---------------------------------------------------------------------------
// Fused attention + output projection. r7 structure; PV contracts with
// Ut = V*WO^T (+cbias) per head. Epilogue: normalize by l, store fp16
// per-head partial (plain coalesced stores — NO atomics).
// Grid 512 linear; h = id%8 (XCD head locality for Ut).
// ---------------------------------------------------------------------------
__global__ __launch_bounds__(256, 2)
void attn_kernel(const short* __restrict__ Kp, const short* __restrict__ Qp,
                 const short* __restrict__ Ut, _Float16* __restrict__ partial) {
  __shared__ __align__(16) short Pt[2][128][136];
  __shared__ __align__(16) float psum[128][4];

  const int tid  = threadIdx.x;
  const int wave = tid >> 6, lane = tid & 63;
  const int l15  = lane & 15, quad = lane >> 4;

  const int L  = blockIdx.x;
  const int h  = L & 7;
  const int b  = (L >> 3) & 3;
  const int q0 = (L >> 5) * 128;

  const short* Kbh = Kp + (long)b * T * DM + h * DK;
  const short* Qbh = Qp + (long)b * T * DM + h * DK;
  const short* Ubh = Ut + ((long)b * 2048 + h * 256) * 2048;

  float4v acc[4][8];
  for (int i = 0; i < 4; i++)
    for (int j = 0; j < 8; j++)
      for (int r = 0; r < 4; r++) acc[i][j][r] = 0.f;

  float ps[8];
  for (int i = 0; i < 8; i++) ps[i] = 0.f;

  short8 qf[8];                       // Q fragments: loaded once, persistent
  for (int qs = 0; qs < 8; qs++)
    qf[qs] = *(const short8*)(Qbh + (long)(q0 + qs*16 + l15) * DM + quad*8);

  auto computeSt = [&](int s0, int buf) {
    for (int ss = 0; ss < 2; ss++) {
      short8 kf = *(const short8*)(Kbh + (long)(s0 + wave*32 + ss*16 + l15) * DM + quad*8);
      for (int qs = 0; qs < 8; qs++) {
        float4v z = {0.f, 0.f, 0.f, 0.f};
        float4v st = __builtin_amdgcn_mfma_f32_16x16x32_bf16(kf, qf[qs], z, 0, 0, 0);
        float p0 = fexp2(st[0]), p1 = fexp2(st[1]);
        float p2 = fexp2(st[2]), p3 = fexp2(st[3]);
        ps[qs] += (p0 + p1) + (p2 + p3);
        uint2v pb; pb[0] = pk2(p0, p1); pb[1] = pk2(p2, p3);
        *(uint2v*)&Pt[buf][qs*16 + l15][wave*32 + ss*16 + quad*4] = pb;
      }
    }
  };

  computeSt(0, 0);

  for (int it = 0; it < T / 128; it++) {
    const int buf = it & 1;
    const int s0  = it * 128;
    __syncthreads();
    if (it < T / 128 - 1) computeSt(s0 + 128, buf ^ 1);
    for (int ks = 0; ks < 4; ks++) {
      short8 pf[8];
      for (int ns = 0; ns < 8; ns++)
        pf[ns] = *(const short8*)&Pt[buf][ns*16 + l15][ks*32 + quad*8];
      for (int ms = 0; ms < 4; ms++) {
        short8 vf = *(const short8*)(Ubh + (long)(wave*64 + ms*16 + l15) * 2048
                                     + s0 + ks*32 + quad*8);
        for (int ns = 0; ns < 8; ns++)
          acc[ms][ns] = __builtin_amdgcn_mfma_f32_16x16x32_bf16(vf, pf[ns], acc[ms][ns], 0, 0, 0);
      }
    }
  }

  for (int qs = 0; qs < 8; qs++) {
    ps[qs] += __shfl_xor(ps[qs], 16, 64);
    ps[qs] += __shfl_xor(ps[qs], 32, 64);
  }
  if (lane < 16)
    for (int qs = 0; qs < 8; qs++) psum[qs*16 + lane][wave] = ps[qs];
  __syncthreads();

  for (int ns = 0; ns < 8; ns++) {
    float4v sv = *(const float4v*)&psum[ns*16 + l15][0];
    float rl = 1.0f / (sv[0] + sv[1] + sv[2] + sv[3]);
    long pbase = ((long)h * 8192 + b * T + q0 + ns*16 + l15) * 256;
    for (int ms = 0; ms < 4; ms++) {
      int ncol = wave*64 + ms*16 + quad*4;
      half4 hv;
      for (int r = 0; r < 4; r++) hv[r] = (_Float16)(acc[ms][ns][r] * rl);
      *(half4*)(partial + pbase + ncol) = hv;
    }
  }
}

// ---------------------------------------------------------------------------
// out[row][n] = WO_b[n] + sum_h partial[h][row][n]; float4/half4 vectorized.
// ---------------------------------------------------------------------------
__global__ void reduce_out(const _Float16* __restrict__ partial,
                           const float* __restrict__ WO_b,
                           float* __restrict__ out) {
  const long HP = 8192L * 256;
  long i4 = ((long)blockIdx.x * 256 + threadIdx.x) * 4;
  float4v o = *(const float4v*)(WO_b + (i4 & 255));
  for (int h = 0; h < 8; h++) {
    half4 hv = *(const half4*)(partial + h * HP + i4);
    for (int r = 0; r < 4; r++) o[r] += (float)hv[r];
  }
  *(float4v*)(out + i4) = o;
}

// ---------------------------------------------------------------------------
extern "C" void kernel_launch(void* const* d_in, const int* in_sizes, int n_in,
                              void* d_out, int out_size, void* d_ws, size_t ws_size,
                              hipStream_t stream) {
  const float* key_x   = (const float*)d_in[0];
  const float* query_x = (const float*)d_in[1];
  const float* value_x = (const float*)d_in[2];
  const float* WK_w = (const float*)d_in[4];
  const float* WK_b = (const float*)d_in[5];
  const float* WQ_w = (const float*)d_in[6];
  const float* WQ_b = (const float*)d_in[7];
  const float* WV_w = (const float*)d_in[8];
  const float* WV_b = (const float*)d_in[9];
  const float* WO_w = (const float*)d_in[10];
  const float* WO_b = (const float*)d_in[11];

  char* ws = (char*)d_ws;
  short*     Kp    = (short*)(ws);                  //  4 MB  [8192][256] bf16
  short*     Qp    = (short*)(ws + (4u  << 20));    //  4 MB  [8192][256] bf16 (x log2e)
  short*     Ut    = (short*)(ws + (8u  << 20));    // 32 MB  [4][2048][2048] bf16
  short*     Wf    = (short*)(ws + (40u << 20));    //  1 MB  [8*256][256] bf16
  float*     cbias = (float*)(ws + (41u << 20));    //  8 KB  [8][256] fp32
  _Float16*  part  = (_Float16*)(ws + (42u << 20)); // 32 MB  [8][8192][256] fp16
  float*     outp  = (float*)d_out;

  prep<<<704, 256, 0, stream>>>(key_x, query_x, WK_w, WK_b, WQ_w, WQ_b,
                                WV_w, WV_b, WO_w, Kp, Qp, Wf, cbias);
  gemm_ut<<<dim3(16, 64), 256, 0, stream>>>(Wf, value_x, cbias, Ut);
  attn_kernel<<<dim3(512), 256, 0, stream>>>(Kp, Qp, Ut, part);
  reduce_out<<<2048, 256, 0, stream>>>(part, WO_b, outp);
}